// Round 21
// baseline (332.448 us; speedup 1.0000x reference)
//
#include <hip/hip_runtime.h>
#include <hip/hip_bf16.h>

#define SEGS   16384
#define DCH    128
#define CHUNK  32
#define SEGPB  4          // consecutive segments per block (measured optimum)
#define XHBLK  520        // frag-layout block stride in shorts (8 blocks of 512+8 pad)
#define LOG2E  1.4426950408889634f

using f32x4  = __attribute__((ext_vector_type(4))) float;
using bf16x8 = __attribute__((ext_vector_type(8))) short;
using u32x2  = __attribute__((ext_vector_type(2))) unsigned int;
using u32x4  = __attribute__((ext_vector_type(4))) unsigned int;

__device__ __forceinline__ float u2f(unsigned int u) { return __uint_as_float(u); }
__device__ __forceinline__ unsigned int f2u(float f) { return __float_as_uint(f); }

// ---------------------------------------------------------------------------
// Setup: (a) W' = W * log2e -> fragment-ready bf16 (RTNE) B layout
//        (b) per-segment row starts via binary search on sorted index
// ---------------------------------------------------------------------------
__global__ void setup_kernel(const float* __restrict__ W,
                             const int* __restrict__ index, int N,
                             unsigned short* __restrict__ WfH,
                             int* __restrict__ seg_start) {
  int i = blockIdx.x * blockDim.x + threadIdx.x;
  if (i < DCH * DCH) {
    int n = i >> 7, k = i & 127;           // W[n][k]
    float w = W[i] * LOG2E;                // fold log2e -> raw exp2 in softmax
    unsigned int u = f2u(w);
    unsigned int r = (u + 0x7FFFu + ((u >> 16) & 1)) >> 16;  // RTNE bf16
    int kt    = k >> 5;
    int ntile = n >> 4;
    int lane  = (n & 15) + 16 * ((k >> 3) & 3);
    int j     = k & 7;
    int dst = ((kt * 8 + ntile) * 64 + lane) * 8 + j;
    WfH[dst] = (unsigned short)r;
  } else if (i < DCH * DCH + SEGS + 1) {
    int s = i - DCH * DCH;                 // lower_bound(index, s)
    int lo = 0, hi = N;
    while (lo < hi) {
      int mid = (lo + hi) >> 1;
      if (index[mid] < s) lo = mid + 1; else hi = mid;
    }
    seg_start[s] = lo;
  }
}

// ---------------------------------------------------------------------------
// Main: block b owns segments [4b, 4b+4) = contiguous rows [R0, R1).
// Streaming 32-row chunks (may cross segment boundaries; block-uniform masked
// sweep flushes per-segment results). NO xf plane: e*x reads bf16 x straight
// from the frag-layout xh (u32 reads, uniform-shift extract). xh double-
// buffered (2 x 8.3 KB) -> ONE raw barrier per chunk; depth-1 register
// prefetch stays in flight across it (no vmcnt drain).
// __launch_bounds__(256, 6): cap VGPR at <=84 so 6 waves/SIMD fit -> 6
// resident blocks/CU (was 5) -> +20% concurrent memory streams (the kernel
// is stream-count-bound: avg outstanding VMEM/CU ~6.5 KB < ~9.2 KB needed
// to saturate the per-CU HBM share).
// ---------------------------------------------------------------------------
__global__ __launch_bounds__(256, 6) void pool_kernel(
    const float* __restrict__ x, const float* __restrict__ bias,
    const int* __restrict__ seg_start,
    const u32x4* __restrict__ WfH,
    float* __restrict__ out) {
  __shared__ unsigned short xh[2][8 * XHBLK];   // 2 x 8.32 KB

  const int t    = threadIdx.x;
  const int wv   = t >> 6;
  const int lane = t & 63;
  const int cl   = lane & 15;              // C col within 16-tile (channel)
  const int g    = lane >> 4;              // lane group (k-slice / row group)
  const int k31  = t & 31;                 // staging lane-in-phase
  const int lrow = t >> 5;                 // staging rows 0..7 (+8 per p)
  const int lcol = k31 << 2;               // staging col (4 floats)

  const int xh_base   = 1040 * (k31 >> 3) + 8 * lrow + 128 * ((k31 >> 1) & 3) + 4 * (k31 & 1);
  const int frag_base = lane * 8;          // shorts
  // e*x read base in DWORDS: x[row=mt*16+g*4+r][d=wv*32+nt*16+cl] ->
  //   dword (exd + mt*260 + nt*128 + r*4), short parity = cl&1
  const int exd = wv * 520 + 16 * g + 64 * (cl >> 3) + ((cl & 7) >> 1);
  const int shl = (cl & 1) ? 0 : 16;       // uniform per lane

  // Register-resident W fragments (this wave's 32 channels).
  u32x4 bh[4][2];
#pragma unroll
  for (int kt = 0; kt < 4; ++kt)
#pragma unroll
    for (int nt = 0; nt < 2; ++nt) {
      int off = (kt * 8 + (wv * 2 + nt)) * 64 + lane;   // 16B units
      bh[kt][nt] = WfH[off];
    }

  const float bc0 = bias[wv * 32 + cl]      * LOG2E;
  const float bc1 = bias[wv * 32 + 16 + cl] * LOG2E;

  const int s0   = blockIdx.x * SEGPB;
  const int sEnd = s0 + SEGPB;
  const int R0   = seg_start[s0];
  const int R1   = seg_start[sEnd];

  if (R0 == R1) {                          // whole block empty -> zeros
    if (lane < 16) {
      for (int es = s0; es < sEnd; ++es) {
        out[(size_t)es * DCH + wv * 32 + cl]      = 0.f;
        out[(size_t)es * DCH + wv * 32 + 16 + cl] = 0.f;
      }
    }
    return;
  }

  int curSeg = s0;
  int segEnd = seg_start[curSeg + 1];
  int c0 = R0;

  // Prefetch first chunk (rows >= R1 zero-filled).
  f32x4 pv[4];
#pragma unroll
  for (int p = 0; p < 4; ++p) {
    int lr = c0 + lrow + p * 8;
    f32x4 v = {0.f, 0.f, 0.f, 0.f};
    if (lr < R1) v = *(const f32x4*)(x + (size_t)lr * DCH + lcol);
    pv[p] = v;
  }

  float den[2] = {0.f, 0.f};
  float num[2] = {0.f, 0.f};

  // One pipeline step on buffer XH. Returns false when all segments flushed.
  auto body = [&](unsigned short* XH) -> bool {
    const unsigned int* XHd = (const unsigned int*)XH;

    // ---- PHASE W: convert pv -> XH (frag layout, round-half-up bf16) ----
#pragma unroll
    for (int p = 0; p < 4; ++p) {
      f32x4 v = pv[p];
      unsigned int u0 = f2u(v[0]) + 0x8000u, u1 = f2u(v[1]) + 0x8000u;
      unsigned int u2 = f2u(v[2]) + 0x8000u, u3 = f2u(v[3]) + 0x8000u;
      u32x2 H = { (u1 & 0xFFFF0000u) | (u0 >> 16),
                  (u3 & 0xFFFF0000u) | (u2 >> 16) };
      *(u32x2*)&XH[xh_base + (p >> 1) * XHBLK + (p & 1) * 64] = H;
    }

    // ---- issue next chunk's loads (linear stream; cross the barrier) ----
    const int nc0 = c0 + CHUNK;
    if (nc0 < R1) {
#pragma unroll
      for (int p = 0; p < 4; ++p) {
        int lr = nc0 + lrow + p * 8;
        f32x4 v = {0.f, 0.f, 0.f, 0.f};
        if (lr < R1) v = *(const f32x4*)(x + (size_t)lr * DCH + lcol);
        pv[p] = v;
      }
    }

    // ---- single barrier: XH writes visible; prefetch NOT drained ----
    asm volatile("s_waitcnt lgkmcnt(0)" ::: "memory");
    __builtin_amdgcn_sched_barrier(0);
    __builtin_amdgcn_s_barrier();
    __builtin_amdgcn_sched_barrier(0);

    // ---- PHASE R: att' = x @ W'^T + b' (this wave's 32 channels) ----
    f32x4 Cf[2][2];
#pragma unroll
    for (int mt = 0; mt < 2; ++mt) {
      Cf[mt][0] = (f32x4){bc0, bc0, bc0, bc0};
      Cf[mt][1] = (f32x4){bc1, bc1, bc1, bc1};
    }
#pragma unroll
    for (int kt = 0; kt < 4; ++kt) {
      u32x4 ah[2];
#pragma unroll
      for (int mt = 0; mt < 2; ++mt)
        ah[mt] = *(const u32x4*)&XH[frag_base + (2 * kt + mt) * XHBLK];
#pragma unroll
      for (int mt = 0; mt < 2; ++mt)
#pragma unroll
        for (int nt = 0; nt < 2; ++nt) {
          bf16x8 A = __builtin_bit_cast(bf16x8, ah[mt]);
          bf16x8 B = __builtin_bit_cast(bf16x8, bh[kt][nt]);
          Cf[mt][nt] = __builtin_amdgcn_mfma_f32_16x16x32_bf16(A, B, Cf[mt][nt], 0, 0, 0);
        }
    }

    // ---- p = exp2(att'); xv via u32 reads (ds_read2-mergeable) ----
    // C layout: col = lane&15 (channel), row(in 16-tile) = g*4 + reg [m89/m91]
    float pr[2][2][4], xv[2][2][4];
#pragma unroll
    for (int nt = 0; nt < 2; ++nt)
#pragma unroll
      for (int mt = 0; mt < 2; ++mt)
#pragma unroll
        for (int r = 0; r < 4; ++r) {
          pr[nt][mt][r] = __builtin_amdgcn_exp2f(Cf[mt][nt][r]);
          unsigned int xu = XHd[exd + mt * 260 + nt * 128 + r * 4];
          xv[nt][mt][r] = u2f((xu << shl) & 0xFFFF0000u);
        }

    // ---- segment sweep (block-uniform control flow) ----
    const int lim = c0 + CHUNK;
    int lo = c0;
    while (curSeg < sEnd) {
      const int hi  = segEnd;
      const int hiC = (hi < lim) ? hi : lim;
      const unsigned span = (unsigned)(hiC - lo);
#pragma unroll
      for (int nt = 0; nt < 2; ++nt)
#pragma unroll
        for (int mt = 0; mt < 2; ++mt)
#pragma unroll
          for (int r = 0; r < 4; ++r) {
            const int row = c0 + mt * 16 + g * 4 + r;
            const bool use = (unsigned)(row - lo) < span;
            const float pp = use ? pr[nt][mt][r] : 0.f;
            den[nt] += pp;
            num[nt] += pp * xv[nt][mt][r];
          }
      if (hi <= lim) {                     // segment ends in this chunk: flush
#pragma unroll
        for (int nt = 0; nt < 2; ++nt) {
          float l = den[nt], a = num[nt];
          l += __shfl_xor(l, 16); l += __shfl_xor(l, 32);
          a += __shfl_xor(a, 16); a += __shfl_xor(a, 32);
          if (lane < 16)
            out[(size_t)curSeg * DCH + wv * 32 + nt * 16 + cl] = a / (l + 1e-16f);
          den[nt] = 0.f; num[nt] = 0.f;
        }
        lo = hi;
        ++curSeg;
        if (curSeg < sEnd) segEnd = seg_start[curSeg + 1];
      } else {
        break;                             // segment continues into next chunk
      }
    }
    if (curSeg >= sEnd) return false;      // all segments flushed -> done
    c0 = nc0;
    return true;
  };

  for (;;) {
    if (!body(&xh[0][0])) break;           // even chunks use buffer 0
    if (!body(&xh[1][0])) break;           // odd chunks use buffer 1
  }
}

extern "C" void kernel_launch(void* const* d_in, const int* in_sizes, int n_in,
                              void* d_out, int out_size, void* d_ws, size_t ws_size,
                              hipStream_t stream) {
  const float* x    = (const float*)d_in[0];
  const float* W    = (const float*)d_in[1];
  const float* bias = (const float*)d_in[2];
  const int*   idx  = (const int*)d_in[3];
  const int N = in_sizes[0] / DCH;

  unsigned short* WfH = (unsigned short*)d_ws;            // 32 KB
  int* seg = (int*)(WfH + DCH * DCH);                     // (SEGS+1)*4 B

  int setup_threads = DCH * DCH + SEGS + 1;
  setup_kernel<<<(setup_threads + 255) / 256, 256, 0, stream>>>(W, idx, N, WfH, seg);
  pool_kernel<<<SEGS / SEGPB, 256, 0, stream>>>(x, bias, seg,
                                                (const u32x4*)WfH,
                                                (float*)d_out);
}

// Round 22
// 116.656 us; speedup vs baseline: 2.8498x; 2.8498x over previous
//
#include <hip/hip_runtime.h>
#include <hip/hip_bf16.h>

#define SEGS   16384
#define DCH    128
#define CHUNK  32
#define SEGPB  4          // consecutive segments per block (measured optimum)
#define XHBLK  520        // frag-layout block stride in shorts (8 blocks of 512+8 pad)
#define LOG2E  1.4426950408889634f

using f32x4  = __attribute__((ext_vector_type(4))) float;
using bf16x8 = __attribute__((ext_vector_type(8))) short;
using u32x2  = __attribute__((ext_vector_type(2))) unsigned int;
using u32x4  = __attribute__((ext_vector_type(4))) unsigned int;

__device__ __forceinline__ float u2f(unsigned int u) { return __uint_as_float(u); }
__device__ __forceinline__ unsigned int f2u(float f) { return __float_as_uint(f); }

// ---------------------------------------------------------------------------
// Setup: (a) W' = W * log2e -> fragment-ready bf16 (RTNE) B layout
//        (b) per-segment row starts via binary search on sorted index
// ---------------------------------------------------------------------------
__global__ void setup_kernel(const float* __restrict__ W,
                             const int* __restrict__ index, int N,
                             unsigned short* __restrict__ WfH,
                             int* __restrict__ seg_start) {
  int i = blockIdx.x * blockDim.x + threadIdx.x;
  if (i < DCH * DCH) {
    int n = i >> 7, k = i & 127;           // W[n][k]
    float w = W[i] * LOG2E;                // fold log2e -> raw exp2 in softmax
    unsigned int u = f2u(w);
    unsigned int r = (u + 0x7FFFu + ((u >> 16) & 1)) >> 16;  // RTNE bf16
    int kt    = k >> 5;
    int ntile = n >> 4;
    int lane  = (n & 15) + 16 * ((k >> 3) & 3);
    int j     = k & 7;
    int dst = ((kt * 8 + ntile) * 64 + lane) * 8 + j;
    WfH[dst] = (unsigned short)r;
  } else if (i < DCH * DCH + SEGS + 1) {
    int s = i - DCH * DCH;                 // lower_bound(index, s)
    int lo = 0, hi = N;
    while (lo < hi) {
      int mid = (lo + hi) >> 1;
      if (index[mid] < s) lo = mid + 1; else hi = mid;
    }
    seg_start[s] = lo;
  }
}

// ---------------------------------------------------------------------------
// Main (FINAL, = R17): block b owns segments [4b, 4b+4) = contiguous rows
// [R0, R1). Streaming 32-row chunks (may cross segment boundaries;
// block-uniform masked sweep flushes per-segment results). NO xf plane:
// e*x reads bf16 x straight from the frag-layout xh (u32 reads,
// uniform-shift extract). xh double-buffered (2 x 8.3 KB) -> ONE raw
// barrier per chunk; depth-1 register prefetch stays in flight across it
// (no vmcnt drain). Staging converts with round-half-up bf16 (err <= 2^-9).
//
// Design notes from the session (what was tried and lost):
//  - CHUNK=64 (4-wave or 8-wave): footprint/barrier-domain growth loses
//  - depth-2 prefetch: extra live state loses; latency already hidden by TLP
//  - SEGPB {2,8,16}: 4 is the prologue/tail optimum
//  - __launch_bounds__ forcing occupancy: allocator spills catastrophically
// ---------------------------------------------------------------------------
__global__ __launch_bounds__(256) void pool_kernel(
    const float* __restrict__ x, const float* __restrict__ bias,
    const int* __restrict__ seg_start,
    const u32x4* __restrict__ WfH,
    float* __restrict__ out) {
  __shared__ unsigned short xh[2][8 * XHBLK];   // 2 x 8.32 KB

  const int t    = threadIdx.x;
  const int wv   = t >> 6;
  const int lane = t & 63;
  const int cl   = lane & 15;              // C col within 16-tile (channel)
  const int g    = lane >> 4;              // lane group (k-slice / row group)
  const int k31  = t & 31;                 // staging lane-in-phase
  const int lrow = t >> 5;                 // staging rows 0..7 (+8 per p)
  const int lcol = k31 << 2;               // staging col (4 floats)

  const int xh_base   = 1040 * (k31 >> 3) + 8 * lrow + 128 * ((k31 >> 1) & 3) + 4 * (k31 & 1);
  const int frag_base = lane * 8;          // shorts
  // e*x read base in DWORDS: x[row=mt*16+g*4+r][d=wv*32+nt*16+cl] ->
  //   dword (exd + mt*260 + nt*128 + r*4), short parity = cl&1
  const int exd = wv * 520 + 16 * g + 64 * (cl >> 3) + ((cl & 7) >> 1);
  const int shl = (cl & 1) ? 0 : 16;       // uniform per lane

  // Register-resident W fragments (this wave's 32 channels).
  u32x4 bh[4][2];
#pragma unroll
  for (int kt = 0; kt < 4; ++kt)
#pragma unroll
    for (int nt = 0; nt < 2; ++nt) {
      int off = (kt * 8 + (wv * 2 + nt)) * 64 + lane;   // 16B units
      bh[kt][nt] = WfH[off];
    }

  const float bc0 = bias[wv * 32 + cl]      * LOG2E;
  const float bc1 = bias[wv * 32 + 16 + cl] * LOG2E;

  const int s0   = blockIdx.x * SEGPB;
  const int sEnd = s0 + SEGPB;
  const int R0   = seg_start[s0];
  const int R1   = seg_start[sEnd];

  if (R0 == R1) {                          // whole block empty -> zeros
    if (lane < 16) {
      for (int es = s0; es < sEnd; ++es) {
        out[(size_t)es * DCH + wv * 32 + cl]      = 0.f;
        out[(size_t)es * DCH + wv * 32 + 16 + cl] = 0.f;
      }
    }
    return;
  }

  int curSeg = s0;
  int segEnd = seg_start[curSeg + 1];
  int c0 = R0;

  // Prefetch first chunk (rows >= R1 zero-filled).
  f32x4 pv[4];
#pragma unroll
  for (int p = 0; p < 4; ++p) {
    int lr = c0 + lrow + p * 8;
    f32x4 v = {0.f, 0.f, 0.f, 0.f};
    if (lr < R1) v = *(const f32x4*)(x + (size_t)lr * DCH + lcol);
    pv[p] = v;
  }

  float den[2] = {0.f, 0.f};
  float num[2] = {0.f, 0.f};

  // One pipeline step on buffer XH. Returns false when all segments flushed.
  auto body = [&](unsigned short* XH) -> bool {
    const unsigned int* XHd = (const unsigned int*)XH;

    // ---- PHASE W: convert pv -> XH (frag layout, round-half-up bf16) ----
#pragma unroll
    for (int p = 0; p < 4; ++p) {
      f32x4 v = pv[p];
      unsigned int u0 = f2u(v[0]) + 0x8000u, u1 = f2u(v[1]) + 0x8000u;
      unsigned int u2 = f2u(v[2]) + 0x8000u, u3 = f2u(v[3]) + 0x8000u;
      u32x2 H = { (u1 & 0xFFFF0000u) | (u0 >> 16),
                  (u3 & 0xFFFF0000u) | (u2 >> 16) };
      *(u32x2*)&XH[xh_base + (p >> 1) * XHBLK + (p & 1) * 64] = H;
    }

    // ---- issue next chunk's loads (linear stream; cross the barrier) ----
    const int nc0 = c0 + CHUNK;
    if (nc0 < R1) {
#pragma unroll
      for (int p = 0; p < 4; ++p) {
        int lr = nc0 + lrow + p * 8;
        f32x4 v = {0.f, 0.f, 0.f, 0.f};
        if (lr < R1) v = *(const f32x4*)(x + (size_t)lr * DCH + lcol);
        pv[p] = v;
      }
    }

    // ---- single barrier: XH writes visible; prefetch NOT drained ----
    asm volatile("s_waitcnt lgkmcnt(0)" ::: "memory");
    __builtin_amdgcn_sched_barrier(0);
    __builtin_amdgcn_s_barrier();
    __builtin_amdgcn_sched_barrier(0);

    // ---- PHASE R: att' = x @ W'^T + b' (this wave's 32 channels) ----
    f32x4 Cf[2][2];
#pragma unroll
    for (int mt = 0; mt < 2; ++mt) {
      Cf[mt][0] = (f32x4){bc0, bc0, bc0, bc0};
      Cf[mt][1] = (f32x4){bc1, bc1, bc1, bc1};
    }
#pragma unroll
    for (int kt = 0; kt < 4; ++kt) {
      u32x4 ah[2];
#pragma unroll
      for (int mt = 0; mt < 2; ++mt)
        ah[mt] = *(const u32x4*)&XH[frag_base + (2 * kt + mt) * XHBLK];
#pragma unroll
      for (int mt = 0; mt < 2; ++mt)
#pragma unroll
        for (int nt = 0; nt < 2; ++nt) {
          bf16x8 A = __builtin_bit_cast(bf16x8, ah[mt]);
          bf16x8 B = __builtin_bit_cast(bf16x8, bh[kt][nt]);
          Cf[mt][nt] = __builtin_amdgcn_mfma_f32_16x16x32_bf16(A, B, Cf[mt][nt], 0, 0, 0);
        }
    }

    // ---- p = exp2(att'); xv via u32 reads (ds_read2-mergeable) ----
    // C layout: col = lane&15 (channel), row(in 16-tile) = g*4 + reg [m89/m91]
    float pr[2][2][4], xv[2][2][4];
#pragma unroll
    for (int nt = 0; nt < 2; ++nt)
#pragma unroll
      for (int mt = 0; mt < 2; ++mt)
#pragma unroll
        for (int r = 0; r < 4; ++r) {
          pr[nt][mt][r] = __builtin_amdgcn_exp2f(Cf[mt][nt][r]);
          unsigned int xu = XHd[exd + mt * 260 + nt * 128 + r * 4];
          xv[nt][mt][r] = u2f((xu << shl) & 0xFFFF0000u);
        }

    // ---- segment sweep (block-uniform control flow) ----
    const int lim = c0 + CHUNK;
    int lo = c0;
    while (curSeg < sEnd) {
      const int hi  = segEnd;
      const int hiC = (hi < lim) ? hi : lim;
      const unsigned span = (unsigned)(hiC - lo);
#pragma unroll
      for (int nt = 0; nt < 2; ++nt)
#pragma unroll
        for (int mt = 0; mt < 2; ++mt)
#pragma unroll
          for (int r = 0; r < 4; ++r) {
            const int row = c0 + mt * 16 + g * 4 + r;
            const bool use = (unsigned)(row - lo) < span;
            const float pp = use ? pr[nt][mt][r] : 0.f;
            den[nt] += pp;
            num[nt] += pp * xv[nt][mt][r];
          }
      if (hi <= lim) {                     // segment ends in this chunk: flush
#pragma unroll
        for (int nt = 0; nt < 2; ++nt) {
          float l = den[nt], a = num[nt];
          l += __shfl_xor(l, 16); l += __shfl_xor(l, 32);
          a += __shfl_xor(a, 16); a += __shfl_xor(a, 32);
          if (lane < 16)
            out[(size_t)curSeg * DCH + wv * 32 + nt * 16 + cl] = a / (l + 1e-16f);
          den[nt] = 0.f; num[nt] = 0.f;
        }
        lo = hi;
        ++curSeg;
        if (curSeg < sEnd) segEnd = seg_start[curSeg + 1];
      } else {
        break;                             // segment continues into next chunk
      }
    }
    if (curSeg >= sEnd) return false;      // all segments flushed -> done
    c0 = nc0;
    return true;
  };

  for (;;) {
    if (!body(&xh[0][0])) break;           // even chunks use buffer 0
    if (!body(&xh[1][0])) break;           // odd chunks use buffer 1
  }
}

extern "C" void kernel_launch(void* const* d_in, const int* in_sizes, int n_in,
                              void* d_out, int out_size, void* d_ws, size_t ws_size,
                              hipStream_t stream) {
  const float* x    = (const float*)d_in[0];
  const float* W    = (const float*)d_in[1];
  const float* bias = (const float*)d_in[2];
  const int*   idx  = (const int*)d_in[3];
  const int N = in_sizes[0] / DCH;

  unsigned short* WfH = (unsigned short*)d_ws;            // 32 KB
  int* seg = (int*)(WfH + DCH * DCH);                     // (SEGS+1)*4 B

  int setup_threads = DCH * DCH + SEGS + 1;
  setup_kernel<<<(setup_threads + 255) / 256, 256, 0, stream>>>(W, idx, N, WfH, seg);
  pool_kernel<<<SEGS / SEGPB, 256, 0, stream>>>(x, bias, seg,
                                                (const u32x4*)WfH,
                                                (float*)d_out);
}